// Round 3
// baseline (475.652 us; speedup 1.0000x reference)
//
#include <hip/hip_runtime.h>

#define N_TOK 16384
#define HID   4096
#define N_EXP 64
#define TOPK  8

#define SPLIT  4
#define KSLICE (HID / SPLIT)   // 1024
#define CH     32              // h-chunk per stage
#define NCH    (KSLICE / CH)   // 32
#define TB     128             // tokens per block
#define XSTR   132             // xs row stride (floats), 16B-aligned, 2-way-max reads
#define WSTR   68              // ws row stride

// d_out layout (floats, concatenated in reference return order)
#define OFF_WT   (N_TOK * N_EXP)
#define OFF_IDX  (OFF_WT + N_TOK * TOPK)
#define OFF_MASK (OFF_IDX + N_TOK * TOPK)

// ---------------------------------------------------------------------------
// Kernel A: split-K register-tiled fp32 GEMM. router += x @ W^T (partial).
// Grid = 128 token-blocks x SPLIT k-slices. Block tile 128 tok x 64 exp.
// Thread tile 8x4: 3 ds_read_b128 per 32 FMA.
// ---------------------------------------------------------------------------
__global__ __launch_bounds__(256, 2)
void router_gemm(const float* __restrict__ x, const float* __restrict__ W,
                 float* __restrict__ router)
{
    __shared__ __align__(16) float xs[2][CH][XSTR];
    __shared__ __align__(16) float ws[2][CH][WSTR];

    const int tid = threadIdx.x;
    const int tb  = blockIdx.x & 127;    // token block
    const int ks  = blockIdx.x >> 7;     // k slice
    const long t0 = (long)tb * TB;
    const int h0  = ks * KSLICE;

    // compute-role indices
    const int lane = tid & 63;
    const int wv   = tid >> 6;
    const int trow = wv * 16 + (lane >> 4) * 4;  // 0..60 (+64 for 2nd half)
    const int ecol = (lane & 15) * 4;            // 0..60

    // staging-role indices: float4 id f = tid + 256*j; row = f>>3, hq = f&7
    const int tf = tid >> 3;             // 0..31 (x rows advance by 32 per j)
    const int hq = tid & 7;

    const float* xsrc = x + (t0 + tf) * (long)HID + h0 + 4 * hq;
    const float* wsrc = W + (long)tf * HID + h0 + 4 * hq;   // expert rows

    float acc[8][4] = {{0.f}};
    float4 px[4], pw[2];

    // prefetch chunk 0
#pragma unroll
    for (int j = 0; j < 4; ++j) px[j] = *(const float4*)(xsrc + (long)(32 * j) * HID);
#pragma unroll
    for (int j = 0; j < 2; ++j) pw[j] = *(const float4*)(wsrc + (long)(32 * j) * HID);

#pragma unroll
    for (int jj = 0; jj < 4; ++jj) {
#pragma unroll
        for (int j = 0; j < 4; ++j) xs[0][4 * hq + jj][tf + 32 * j] = ((const float*)&px[j])[jj];
#pragma unroll
        for (int j = 0; j < 2; ++j) ws[0][4 * hq + jj][tf + 32 * j] = ((const float*)&pw[j])[jj];
    }
    __syncthreads();

    for (int c = 0; c < NCH; ++c) {
        const int buf = c & 1;

        if (c + 1 < NCH) {   // register prefetch of next chunk
#pragma unroll
            for (int j = 0; j < 4; ++j) px[j] = *(const float4*)(xsrc + (c + 1) * CH + (long)(32 * j) * HID);
#pragma unroll
            for (int j = 0; j < 2; ++j) pw[j] = *(const float4*)(wsrc + (c + 1) * CH + (long)(32 * j) * HID);
        }

#pragma unroll 4
        for (int k = 0; k < CH; ++k) {
            float4 xa = *(const float4*)&xs[buf][k][trow];
            float4 xb = *(const float4*)&xs[buf][k][trow + 64];
            float4 wq = *(const float4*)&ws[buf][k][ecol];
#pragma unroll
            for (int i = 0; i < 4; ++i) {
                float xv = ((const float*)&xa)[i];
                acc[i][0] = fmaf(xv, wq.x, acc[i][0]);
                acc[i][1] = fmaf(xv, wq.y, acc[i][1]);
                acc[i][2] = fmaf(xv, wq.z, acc[i][2]);
                acc[i][3] = fmaf(xv, wq.w, acc[i][3]);
            }
#pragma unroll
            for (int i = 0; i < 4; ++i) {
                float xv = ((const float*)&xb)[i];
                acc[4 + i][0] = fmaf(xv, wq.x, acc[4 + i][0]);
                acc[4 + i][1] = fmaf(xv, wq.y, acc[4 + i][1]);
                acc[4 + i][2] = fmaf(xv, wq.z, acc[4 + i][2]);
                acc[4 + i][3] = fmaf(xv, wq.w, acc[4 + i][3]);
            }
        }

        if (c + 1 < NCH) {   // write prefetched chunk into the other buffer
            const int nb = buf ^ 1;
#pragma unroll
            for (int jj = 0; jj < 4; ++jj) {
#pragma unroll
                for (int j = 0; j < 4; ++j) xs[nb][4 * hq + jj][tf + 32 * j] = ((const float*)&px[j])[jj];
#pragma unroll
                for (int j = 0; j < 2; ++j) ws[nb][4 * hq + jj][tf + 32 * j] = ((const float*)&pw[j])[jj];
            }
        }
        __syncthreads();
    }

    // epilogue: accumulate partial tile into router via HW fp32 atomics
#pragma unroll
    for (int h = 0; h < 2; ++h) {
        float* rbase = router + (t0 + trow + 64 * h) * (long)N_EXP + ecol;
#pragma unroll
        for (int i = 0; i < 4; ++i)
#pragma unroll
            for (int j = 0; j < 4; ++j)
                unsafeAtomicAdd(rbase + (long)i * N_EXP + j, acc[4 * h + i][j]);
    }
}

// ---------------------------------------------------------------------------
// Kernel B: add bias, rewrite router logits, softmax + top-8 (tie -> lowest
// index) + renormalized weights. Wave per token. (Mask written by kernel C.)
// ---------------------------------------------------------------------------
__global__ __launch_bounds__(256)
void router_topk(float* __restrict__ router, const float* __restrict__ b,
                 float* __restrict__ out)
{
    const int tid  = threadIdx.x;
    const int lane = tid & 63;
    const int wv   = tid >> 6;
    const int n    = blockIdx.x * 4 + wv;

    float l = router[(long)n * N_EXP + lane] + b[lane];
    router[(long)n * N_EXP + lane] = l;   // full logit output

    // softmax over 64 experts (one logit per lane)
    float m = l;
#pragma unroll
    for (int o = 32; o > 0; o >>= 1) m = fmaxf(m, __shfl_xor(m, o));
    float p = expf(l - m);
    float Z = p;
#pragma unroll
    for (int o = 32; o > 0; o >>= 1) Z += __shfl_xor(Z, o);
    float prob = p / Z;

    // iterative top-8 via butterfly argmax (lexicographic: max val, min idx)
    float cur = prob;
    float myv = 0.f;
    int   myi = 0;
    float ssum = 0.f;
#pragma unroll
    for (int k = 0; k < TOPK; ++k) {
        float v = cur;
        int   id = lane;
#pragma unroll
        for (int o = 32; o > 0; o >>= 1) {
            float ov = __shfl_xor(v, o);
            int   oi = __shfl_xor(id, o);
            if (ov > v || (ov == v && oi < id)) { v = ov; id = oi; }
        }
        if (lane == k)  { myv = v; myi = id; }
        if (lane == id) cur = -1.f;
        ssum += v;
    }

    if (lane < TOPK) {
        out[OFF_WT  + (long)n * TOPK + lane] = myv / ssum;
        out[OFF_IDX + (long)n * TOPK + lane] = (float)myi;
    }
}

// ---------------------------------------------------------------------------
// Kernel C: dense one-hot mask writer. mask[e][k][n] = (idx[n][k]==e).
// Thread owns (k, 4 consecutive tokens); loops e, float4 coalesced stores.
// Grid 128 blocks x 256 threads = 32768 threads = 8 k x 4096 token-quads.
// ---------------------------------------------------------------------------
__global__ __launch_bounds__(256)
void mask_fill(const float* __restrict__ idxf, float* __restrict__ mask)
{
    const int k  = blockIdx.x >> 4;                      // 0..7
    const int n0 = ((blockIdx.x & 15) * 256 + threadIdx.x) * 4;

    int sel[4];
#pragma unroll
    for (int t = 0; t < 4; ++t)
        sel[t] = (int)idxf[(long)(n0 + t) * TOPK + k];

#pragma unroll 8
    for (int e = 0; e < N_EXP; ++e) {
        float4 v;
        v.x = (sel[0] == e) ? 1.0f : 0.0f;
        v.y = (sel[1] == e) ? 1.0f : 0.0f;
        v.z = (sel[2] == e) ? 1.0f : 0.0f;
        v.w = (sel[3] == e) ? 1.0f : 0.0f;
        *(float4*)(mask + (long)(e * TOPK + k) * N_TOK + n0) = v;
    }
}

extern "C" void kernel_launch(void* const* d_in, const int* in_sizes, int n_in,
                              void* d_out, int out_size, void* d_ws, size_t ws_size,
                              hipStream_t stream)
{
    const float* x = (const float*)d_in[0];
    const float* W = (const float*)d_in[1];
    const float* b = (const float*)d_in[2];
    float* out = (float*)d_out;

    // zero only the router region (atomic accumulation target)
    hipMemsetAsync(out, 0, (size_t)(N_TOK * N_EXP) * sizeof(float), stream);

    hipLaunchKernelGGL(router_gemm, dim3(TB * SPLIT == 512 ? 512 : 512), dim3(256), 0, stream,
                       x, W, out);
    hipLaunchKernelGGL(router_topk, dim3(N_TOK / 4), dim3(256), 0, stream,
                       out, b, out);
    hipLaunchKernelGGL(mask_fill, dim3(128), dim3(256), 0, stream,
                       out + OFF_IDX, out + OFF_MASK);
}